// Round 3
// baseline (1688.269 us; speedup 1.0000x reference)
//
#include <hip/hip_runtime.h>

#define SEQL 4096
#define NB   256
#define NH   64

__device__ __forceinline__ float rl(float v, int lane) {
  return __builtin_bit_cast(float,
      __builtin_amdgcn_readlane(__builtin_bit_cast(int, v), lane));
}

// ---------------------------------------------------------------------------
// Kernel A: xp = x @ W_ih^T + (b_ih + b_hh), classic register-tiled fp32 GEMM.
// No broadcasts, no LDS. Block = 256 threads; thread (tc=t&7, tr=t>>3) owns an
// 8-row x 8-col micro-tile: rows rbase+tr*8..+7, cols tc*8..+7.
// All x/w loads are float4 from ONE base each with compile-time immediate
// offsets (max 2800B < 4096 imm). Lanes sharing tr (or tc) read identical
// addresses -> coalesced broadcast; W (16KB) stays L1-resident.
// Per output: single accumulator initialized to bias, k ascending 0..63 in
// .x.y.z.w order => bit-identical to all previous rounds.
// ---------------------------------------------------------------------------
__global__ __launch_bounds__(256) void xproj(const float* __restrict__ x,
                                             const float* __restrict__ w_ih,
                                             const float* __restrict__ b_ih,
                                             const float* __restrict__ b_hh,
                                             float* __restrict__ dst) {
  const int t  = threadIdx.x;
  const int tc = t & 7;                 // col group: cols tc*8..tc*8+7
  const int tr = t >> 3;                // row group: 0..31
  const size_t rbase = (size_t)blockIdx.x * 256 + (size_t)tr * 8;
  const int c0 = tc * 8;

  float acc[8][8];
#pragma unroll
  for (int cc = 0; cc < 8; ++cc) {
    float b = b_ih[c0 + cc] + b_hh[c0 + cc];   // same order as original
#pragma unroll
    for (int rr = 0; rr < 8; ++rr) acc[rr][cc] = b;
  }

  const float4* xb4 = (const float4*)(x + rbase * NH);          // + rr*16 + kq
  const float4* wb4 = (const float4*)(w_ih + (size_t)c0 * NH);  // + cc*16 + kq

#pragma unroll
  for (int kq = 0; kq < 16; ++kq) {
    float4 wq[8], xq[8];
#pragma unroll
    for (int cc = 0; cc < 8; ++cc) wq[cc] = wb4[cc * 16 + kq];
#pragma unroll
    for (int rr = 0; rr < 8; ++rr) xq[rr] = xb4[rr * 16 + kq];
#pragma unroll
    for (int rr = 0; rr < 8; ++rr)
#pragma unroll
      for (int cc = 0; cc < 8; ++cc) {
        float a = acc[rr][cc];
        a = fmaf(xq[rr].x, wq[cc].x, a);
        a = fmaf(xq[rr].y, wq[cc].y, a);
        a = fmaf(xq[rr].z, wq[cc].z, a);
        a = fmaf(xq[rr].w, wq[cc].w, a);
        acc[rr][cc] = a;
      }
  }

  float* ob = dst + rbase * NH + c0;
#pragma unroll
  for (int rr = 0; rr < 8; ++rr) {
    *(float4*)(ob + rr * NH)     = make_float4(acc[rr][0], acc[rr][1], acc[rr][2], acc[rr][3]);
    *(float4*)(ob + rr * NH + 4) = make_float4(acc[rr][4], acc[rr][5], acc[rr][6], acc[rr][7]);
  }
}

// ---------------------------------------------------------------------------
// Kernel B: sequential scan, one wave per batch row, readlane h-broadcast.
// Change vs round 2: ALL 64 readlanes are batched BEFORE the FMA section and
// pinned with sched_barrier(0). Round-2's measured ~7cy/RL is hypothesized to
// be the VALU-writes-SGPR -> VALU-reads-SGPR hazard: the compiler kept a tiny
// h-window (SGPR_Count=64) so each RL sat right before its consumer. Batching
// makes every RL->consumer distance >= 64 instructions (needs ~96 SGPRs, fits
// the 102 budget). FMA order / tanh bit-identical => absmax must not move.
// ---------------------------------------------------------------------------
#define RSTEP(XQ, PF)                                            \
  {                                                              \
    float xcur = XQ;                                             \
    if (PF) { XQ = px[0]; px += step; }  /* 4-deep prefetch */   \
    float hb[64];                                                \
    _Pragma("unroll")                                            \
    for (int j = 0; j < 64; ++j) hb[j] = rl(hn, j);              \
    __builtin_amdgcn_sched_barrier(0);                           \
    float a0 = xcur, a1 = 0.f, a2 = 0.f, a3 = 0.f;               \
    _Pragma("unroll")                                            \
    for (int m = 0; m < 16; ++m) {                               \
      float4 wv = w[m];                                          \
      a0 = fmaf(wv.x, hb[4 * m + 0], a0);                        \
      a1 = fmaf(wv.y, hb[4 * m + 1], a1);                        \
      a2 = fmaf(wv.z, hb[4 * m + 2], a2);                        \
      a3 = fmaf(wv.w, hb[4 * m + 3], a3);                        \
    }                                                            \
    float z = (a0 + a1) + (a2 + a3);                             \
    z = fminf(15.f, fmaxf(-15.f, z));                            \
    float e2 = __builtin_amdgcn_exp2f(z * 2.885390081777927f);   \
    hn = (e2 - 1.f) * __builtin_amdgcn_rcpf(e2 + 1.f);           \
    po[0] = hn;                                                  \
    po += step;                                                  \
  }

__device__ __forceinline__ void rec_run(const float* __restrict__ w_hh,
                                        const float* __restrict__ xp,
                                        float* __restrict__ out, int b, int i) {
  float4 w[16];
  const float4* wr = (const float4*)(w_hh + (size_t)i * NH);
#pragma unroll
  for (int k = 0; k < 16; ++k) w[k] = wr[k];

  const size_t step = (size_t)NB * NH;
  const float* px = xp + (size_t)b * NH + i;
  float* po = out + (size_t)b * NH + i;

  float xq0 = px[0];
  float xq1 = px[step];
  float xq2 = px[2 * step];
  float xq3 = px[3 * step];
  px += 4 * step;

  float hn = 0.f;

#pragma unroll 1
  for (int s = 0; s < SEQL - 4; s += 4) {
    RSTEP(xq0, 1) RSTEP(xq1, 1) RSTEP(xq2, 1) RSTEP(xq3, 1)
  }
  RSTEP(xq0, 0) RSTEP(xq1, 0) RSTEP(xq2, 0) RSTEP(xq3, 0)
}
#undef RSTEP

__global__ __launch_bounds__(64) void rnn_rec_split(const float* __restrict__ w_hh,
                                                    const float* __restrict__ xp,
                                                    float* __restrict__ out) {
  rec_run(w_hh, xp, out, blockIdx.x, threadIdx.x);
}

__global__ __launch_bounds__(64) void rnn_rec_inpl(const float* __restrict__ w_hh,
                                                   float* __restrict__ out) {
  rec_run(w_hh, out, out, blockIdx.x, threadIdx.x);
}

extern "C" void kernel_launch(void* const* d_in, const int* in_sizes, int n_in,
                              void* d_out, int out_size, void* d_ws, size_t ws_size,
                              hipStream_t stream) {
  const float* x    = (const float*)d_in[0];
  const float* w_ih = (const float*)d_in[1];
  const float* w_hh = (const float*)d_in[2];
  const float* b_ih = (const float*)d_in[3];
  const float* b_hh = (const float*)d_in[4];
  float* out = (float*)d_out;

  const size_t need = (size_t)SEQL * NB * NH * sizeof(float);
  if (d_ws && ws_size >= need) {
    float* xpbuf = (float*)d_ws;
    xproj<<<dim3(4096), dim3(256), 0, stream>>>(x, w_ih, b_ih, b_hh, xpbuf);
    rnn_rec_split<<<dim3(NB), dim3(64), 0, stream>>>(w_hh, xpbuf, out);
  } else {
    xproj<<<dim3(4096), dim3(256), 0, stream>>>(x, w_ih, b_ih, b_hh, out);
    rnn_rec_inpl<<<dim3(NB), dim3(64), 0, stream>>>(w_hh, out);
  }
}